// Round 4
// baseline (459.557 us; speedup 1.0000x reference)
//
#include <hip/hip_runtime.h>
#include <math.h>

#define E_ 8
#define T_ 4096
#define K_ 2048
#define I_ 768
#define TWOI 1536
#define NPAIR (2*T_)

typedef unsigned short u16;
typedef __attribute__((ext_vector_type(8))) __bf16 bf16x8;
typedef __attribute__((ext_vector_type(4))) float f32x4;
typedef __attribute__((ext_vector_type(8))) u16 u16x8;
typedef __attribute__((ext_vector_type(4))) int int4v;
typedef __attribute__((ext_vector_type(4))) float float4v;

typedef __attribute__((address_space(3))) u16 lds_u16;
typedef __attribute__((address_space(1))) const u16 g_u16;

__device__ inline void gld16(const u16* g, u16* l) {
    __builtin_amdgcn_global_load_lds((g_u16*)g, (lds_u16*)l, 16, 0, 0);
}

#define VMW8 asm volatile("s_waitcnt vmcnt(8)" ::: "memory")
#define VMW0 asm volatile("s_waitcnt vmcnt(0)" ::: "memory")
#define BARX do { __builtin_amdgcn_s_barrier(); __builtin_amdgcn_sched_barrier(0); } while (0)

__device__ inline u16 f2bf(float x) {
    unsigned u = __builtin_bit_cast(unsigned, x);
    unsigned r = 0x7fffu + ((u >> 16) & 1u);
    u += r;
    return (u16)(u >> 16);
}
__device__ inline float bf2f(u16 b) {
    unsigned u = ((unsigned)b) << 16;
    return __builtin_bit_cast(float, u);
}

// ---------------- routing ----------------
__global__ void k_zero(int* __restrict__ p, int n) {
    int i = blockIdx.x * 256 + threadIdx.x;
    if (i < n) p[i] = 0;
}

__global__ void k_route(const float* __restrict__ logits, int* __restrict__ tid2,
                        float* __restrict__ tw, int* __restrict__ counts) {
    int t = blockIdx.x * 256 + threadIdx.x;
    if (t >= T_) return;
    float l[E_];
#pragma unroll
    for (int e = 0; e < E_; ++e) l[e] = logits[t * E_ + e];
    int i0 = 0; float m0 = l[0];
#pragma unroll
    for (int e = 1; e < E_; ++e) if (l[e] > m0) { m0 = l[e]; i0 = e; }
    int i1 = -1; float m1 = -1e30f;
#pragma unroll
    for (int e = 0; e < E_; ++e) if (e != i0 && l[e] > m1) { m1 = l[e]; i1 = e; }
    float w0 = 1.0f / (1.0f + expf(m1 - m0));
    float w1 = 1.0f - w0;
    tid2[t * 2 + 0] = i0; tid2[t * 2 + 1] = i1;
    tw[t * 2 + 0] = w0;  tw[t * 2 + 1] = w1;
    atomicAdd(&counts[i0], 1);
    atomicAdd(&counts[i1], 1);
}

__global__ void k_scan(const int* __restrict__ counts, int* __restrict__ offsets) {
    if (threadIdx.x == 0) {
        int s = 0;
        for (int e = 0; e < E_; ++e) { offsets[e] = s; s += counts[e]; }
        offsets[E_] = s;
    }
}

__global__ void k_lists(const int* __restrict__ tid2, const int* __restrict__ offsets,
                        int* __restrict__ cursors, int* __restrict__ pairTok) {
    int t = blockIdx.x * 256 + threadIdx.x;
    if (t >= T_) return;
#pragma unroll
    for (int s = 0; s < 2; ++s) {
        int e = tid2[t * 2 + s];
        int pos = atomicAdd(&cursors[e], 1);
        pairTok[offsets[e] + pos] = (t << 1) | s;
    }
}

// ---------------- dequant conversions ----------------
__global__ void k_cvt_w13(const int* __restrict__ q, const float* __restrict__ alpha,
                          u16* __restrict__ wb) {
    long idx = ((long)blockIdx.x * 256 + threadIdx.x) * 8;
    int k = (int)(idx & (K_ - 1));
    int e = (int)(idx / ((long)TWOI * K_));
    const int4v* qp = (const int4v*)(q + idx);
    int4v q0 = qp[0], q1 = qp[1];
    const float4v* ap = (const float4v*)(alpha + e * K_ + k);
    float4v a0 = ap[0], a1 = ap[1];
    u16x8 r;
    r[0] = f2bf((float)(q0[0] - 1) * a0[0]);
    r[1] = f2bf((float)(q0[1] - 1) * a0[1]);
    r[2] = f2bf((float)(q0[2] - 1) * a0[2]);
    r[3] = f2bf((float)(q0[3] - 1) * a0[3]);
    r[4] = f2bf((float)(q1[0] - 1) * a1[0]);
    r[5] = f2bf((float)(q1[1] - 1) * a1[1]);
    r[6] = f2bf((float)(q1[2] - 1) * a1[2]);
    r[7] = f2bf((float)(q1[3] - 1) * a1[3]);
    *(u16x8*)(wb + idx) = r;
}

__global__ void k_cvt_w2(const int* __restrict__ q, const float* __restrict__ alpha,
                         u16* __restrict__ wb) {
    long idx = ((long)blockIdx.x * 256 + threadIdx.x) * 8;
    int i = (int)(idx % I_);
    int e = (int)(idx / ((long)K_ * I_));
    const int4v* qp = (const int4v*)(q + idx);
    int4v q0 = qp[0], q1 = qp[1];
    const float4v* ap = (const float4v*)(alpha + e * I_ + i);
    float4v a0 = ap[0], a1 = ap[1];
    u16x8 r;
    r[0] = f2bf((float)(q0[0] - 1) * a0[0]);
    r[1] = f2bf((float)(q0[1] - 1) * a0[1]);
    r[2] = f2bf((float)(q0[2] - 1) * a0[2]);
    r[3] = f2bf((float)(q0[3] - 1) * a0[3]);
    r[4] = f2bf((float)(q1[0] - 1) * a1[0]);
    r[5] = f2bf((float)(q1[1] - 1) * a1[1]);
    r[6] = f2bf((float)(q1[2] - 1) * a1[2]);
    r[7] = f2bf((float)(q1[3] - 1) * a1[3]);
    *(u16x8*)(wb + idx) = r;
}

__global__ void k_cvt_x(const float* __restrict__ x, u16* __restrict__ xb) {
    long idx = ((long)blockIdx.x * 256 + threadIdx.x) * 8;
    const float4v* xp = (const float4v*)(x + idx);
    float4v x0 = xp[0], x1 = xp[1];
    u16x8 r;
    r[0] = f2bf(x0[0]); r[1] = f2bf(x0[1]); r[2] = f2bf(x0[2]); r[3] = f2bf(x0[3]);
    r[4] = f2bf(x1[0]); r[5] = f2bf(x1[1]); r[6] = f2bf(x1[2]); r[7] = f2bf(x1[3]);
    *(u16x8*)(xb + idx) = r;
}

#define BM 128
#define BK 64

// ---------------- grouped GEMM1 + silu*up ----------------
// 3-buffer counted-vmcnt pipeline + T2 XOR swizzle (pre-swizzled source).
__global__ __launch_bounds__(256) void k_gemm1(
    const u16* __restrict__ xb,       // [T][K]
    const u16* __restrict__ wb13,     // [E][2I][K]
    const int* __restrict__ pairTok, const int* __restrict__ offsets,
    u16* __restrict__ ab)             // [NPAIR][I] (list order)
{
    int bid = blockIdx.x;
    int e = bid & 7;
    int r_ = bid >> 3;
    int n0 = (r_ >> 5) * 64;
    int m0 = (r_ & 31) * BM;

    int base = offsets[e];
    int cnt = offsets[e + 1] - base;
    if (m0 >= cnt) return;

    __shared__ __attribute__((aligned(16))) u16 As[3][BM][BK];  // 48 KB
    __shared__ __attribute__((aligned(16))) u16 Bg[3][64][BK];  // 24 KB
    __shared__ __attribute__((aligned(16))) u16 Bu[3][64][BK];  // 24 KB

    int tid = threadIdx.x;
    int lane = tid & 63, wid = tid >> 6;
    int wm = wid >> 1, wn = wid & 1;
    int lr = lane >> 3;                                   // row within 8-row chunk
    int lcs = (((lane & 7) ^ ((lane >> 3) & 7)) * 8);     // inverse-swizzled src col

    const u16* aSrc[4]; int aOff[4];
#pragma unroll
    for (int j = 0; j < 4; ++j) {
        int c = wid * 4 + j;                 // A chunk 0..15 (8 rows each)
        int m = m0 + c * 8 + lr;
        if (m >= cnt) m = cnt - 1;
        int tok = pairTok[base + m] >> 1;
        aSrc[j] = xb + (long)tok * K_ + lcs;
        aOff[j] = c * 512;
    }
    const u16* gSrc[2]; int bOff[2];
#pragma unroll
    for (int j = 0; j < 2; ++j) {
        int c = wid * 2 + j;                 // B chunk 0..7
        int row = n0 + c * 8 + lr;
        gSrc[j] = wb13 + ((long)e * TWOI + row) * K_ + lcs;
        bOff[j] = c * 512;
    }

    f32x4 accg[4][2], accu[4][2];
#pragma unroll
    for (int mi = 0; mi < 4; ++mi)
#pragma unroll
        for (int ni = 0; ni < 2; ++ni) {
            accg[mi][ni] = (f32x4){0.f, 0.f, 0.f, 0.f};
            accu[mi][ni] = (f32x4){0.f, 0.f, 0.f, 0.f};
        }

    auto stage = [&](int b, int ks) {
        int k0 = ks * BK;
#pragma unroll
        for (int j = 0; j < 4; ++j) gld16(aSrc[j] + k0, &As[b][0][0] + aOff[j]);
#pragma unroll
        for (int j = 0; j < 2; ++j) {
            gld16(gSrc[j] + k0, &Bg[b][0][0] + bOff[j]);
            gld16(gSrc[j] + (long)I_ * K_ + k0, &Bu[b][0][0] + bOff[j]);
        }
    };

    int swz = (lane & 7) << 3;  // read-col XOR (elements)
    auto compute = [&](int b) {
#pragma unroll
        for (int kk = 0; kk < 2; ++kk) {
            int kc = (kk * 32 + (lane >> 4) * 8) ^ swz;
            bf16x8 aF[4], bgF[2], buF[2];
#pragma unroll
            for (int mi = 0; mi < 4; ++mi)
                aF[mi] = __builtin_bit_cast(bf16x8,
                    *(const u16x8*)&As[b][wm * 64 + mi * 16 + (lane & 15)][kc]);
#pragma unroll
            for (int ni = 0; ni < 2; ++ni) {
                bgF[ni] = __builtin_bit_cast(bf16x8,
                    *(const u16x8*)&Bg[b][wn * 32 + ni * 16 + (lane & 15)][kc]);
                buF[ni] = __builtin_bit_cast(bf16x8,
                    *(const u16x8*)&Bu[b][wn * 32 + ni * 16 + (lane & 15)][kc]);
            }
#pragma unroll
            for (int mi = 0; mi < 4; ++mi)
#pragma unroll
                for (int ni = 0; ni < 2; ++ni) {
                    accg[mi][ni] = __builtin_amdgcn_mfma_f32_16x16x32_bf16(
                        aF[mi], bgF[ni], accg[mi][ni], 0, 0, 0);
                    accu[mi][ni] = __builtin_amdgcn_mfma_f32_16x16x32_bf16(
                        aF[mi], buF[ni], accu[mi][ni], 0, 0, 0);
                }
        }
    };

    // NT = 32. 3-buffer rotation, counted vmcnt, raw barriers.
    stage(0, 0); stage(1, 1);
    VMW8; BARX;
#pragma unroll 1
    for (int t = 0; t < 30; t += 3) {
        stage(2, t + 2); compute(0); VMW8; BARX;
        stage(0, t + 3); compute(1); VMW8; BARX;
        stage(1, t + 4); compute(2); VMW8; BARX;
    }
    compute(0); VMW0; BARX;
    compute(1);

#pragma unroll
    for (int mi = 0; mi < 4; ++mi)
#pragma unroll
        for (int ni = 0; ni < 2; ++ni)
#pragma unroll
            for (int rg = 0; rg < 4; ++rg) {
                int r = wm * 64 + mi * 16 + (lane >> 4) * 4 + rg;
                if (m0 + r < cnt) {
                    int n = n0 + wn * 32 + ni * 16 + (lane & 15);
                    float g = accg[mi][ni][rg];
                    float u = accu[mi][ni][rg];
                    float a = g / (1.0f + expf(-g)) * u;
                    ab[(long)(base + m0 + r) * I_ + n] = f2bf(a);
                }
            }
}

// ---------------- grouped GEMM2 (128x128, 3-buffer counted pipeline) ----------------
__global__ __launch_bounds__(256) void k_gemm2(
    const u16* __restrict__ ab,       // [NPAIR][I] (list order)
    const u16* __restrict__ wb2,      // [E][K][I]
    const int* __restrict__ pairTok, const int* __restrict__ offsets,
    u16* __restrict__ yb)             // [NPAIR][K] indexed by (t<<1)|slot
{
    int bid = blockIdx.x;
    int e = bid & 7;
    int r_ = bid >> 3;
    int n0 = (r_ >> 5) * 128;
    int m0 = (r_ & 31) * BM;

    int base = offsets[e];
    int cnt = offsets[e + 1] - base;
    if (m0 >= cnt) return;

    __shared__ __attribute__((aligned(16))) u16 As[3][BM][BK];   // 48 KB
    __shared__ __attribute__((aligned(16))) u16 Bs[3][128][BK];  // 48 KB

    int tid = threadIdx.x;
    int lane = tid & 63, wid = tid >> 6;
    int wm = wid >> 1, wn = wid & 1;
    int lr = lane >> 3;
    int lcs = (((lane & 7) ^ ((lane >> 3) & 7)) * 8);

    const u16* aSrc[4]; int aOff[4];
#pragma unroll
    for (int j = 0; j < 4; ++j) {
        int c = wid * 4 + j;
        int m = m0 + c * 8 + lr;
        if (m >= cnt) m = cnt - 1;
        aSrc[j] = ab + (long)(base + m) * I_ + lcs;
        aOff[j] = c * 512;
    }
    const u16* bSrc[4]; int bOff[4];
#pragma unroll
    for (int j = 0; j < 4; ++j) {
        int c = wid * 4 + j;
        int row = n0 + c * 8 + lr;
        bSrc[j] = wb2 + ((long)e * K_ + row) * I_ + lcs;
        bOff[j] = c * 512;
    }

    f32x4 acc[4][4];
#pragma unroll
    for (int mi = 0; mi < 4; ++mi)
#pragma unroll
        for (int ni = 0; ni < 4; ++ni)
            acc[mi][ni] = (f32x4){0.f, 0.f, 0.f, 0.f};

    auto stage = [&](int b, int ks) {
        int k0 = ks * BK;
#pragma unroll
        for (int j = 0; j < 4; ++j) gld16(aSrc[j] + k0, &As[b][0][0] + aOff[j]);
#pragma unroll
        for (int j = 0; j < 4; ++j) gld16(bSrc[j] + k0, &Bs[b][0][0] + bOff[j]);
    };

    int swz = (lane & 7) << 3;
    auto compute = [&](int b) {
#pragma unroll
        for (int kk = 0; kk < 2; ++kk) {
            int kc = (kk * 32 + (lane >> 4) * 8) ^ swz;
            bf16x8 aF[4], bF[4];
#pragma unroll
            for (int mi = 0; mi < 4; ++mi)
                aF[mi] = __builtin_bit_cast(bf16x8,
                    *(const u16x8*)&As[b][wm * 64 + mi * 16 + (lane & 15)][kc]);
#pragma unroll
            for (int ni = 0; ni < 4; ++ni)
                bF[ni] = __builtin_bit_cast(bf16x8,
                    *(const u16x8*)&Bs[b][wn * 64 + ni * 16 + (lane & 15)][kc]);
#pragma unroll
            for (int mi = 0; mi < 4; ++mi)
#pragma unroll
                for (int ni = 0; ni < 4; ++ni)
                    acc[mi][ni] = __builtin_amdgcn_mfma_f32_16x16x32_bf16(
                        aF[mi], bF[ni], acc[mi][ni], 0, 0, 0);
        }
    };

    // NT = 12
    stage(0, 0); stage(1, 1);
    VMW8; BARX;
#pragma unroll 1
    for (int t = 0; t < 9; t += 3) {
        stage(2, t + 2); compute(0); VMW8; BARX;
        stage(0, t + 3); compute(1); VMW8; BARX;
        stage(1, t + 4); compute(2); VMW8; BARX;
    }
    stage(2, 11); compute(0); VMW8; BARX;
    compute(1); VMW0; BARX;
    compute(2);

#pragma unroll
    for (int mi = 0; mi < 4; ++mi)
#pragma unroll
        for (int ni = 0; ni < 4; ++ni)
#pragma unroll
            for (int rg = 0; rg < 4; ++rg) {
                int r = wm * 64 + mi * 16 + (lane >> 4) * 4 + rg;
                if (m0 + r < cnt) {
                    int pt = pairTok[base + m0 + r];
                    int n = n0 + wn * 64 + ni * 16 + (lane & 15);
                    yb[(long)pt * K_ + n] = f2bf(acc[mi][ni][rg]);
                }
            }
}

// ---------------- combine ----------------
__global__ void k_combine(const u16* __restrict__ yb, const float* __restrict__ tw,
                          float* __restrict__ out) {
    long idx = ((long)blockIdx.x * 256 + threadIdx.x) * 8;
    int t = (int)(idx >> 11);
    float w0 = tw[t * 2 + 0];
    float w1 = tw[t * 2 + 1];
    u16x8 y0 = *(const u16x8*)(yb + (long)(2 * t) * K_ + (idx & (K_ - 1)));
    u16x8 y1 = *(const u16x8*)(yb + (long)(2 * t + 1) * K_ + (idx & (K_ - 1)));
    float4v o0, o1;
#pragma unroll
    for (int j = 0; j < 4; ++j) o0[j] = w0 * bf2f(y0[j]) + w1 * bf2f(y1[j]);
#pragma unroll
    for (int j = 0; j < 4; ++j) o1[j] = w0 * bf2f(y0[4 + j]) + w1 * bf2f(y1[4 + j]);
    *(float4v*)(out + idx) = o0;
    *(float4v*)(out + idx + 4) = o1;
}

// ---------------- launch ----------------
extern "C" void kernel_launch(void* const* d_in, const int* in_sizes, int n_in,
                              void* d_out, int out_size, void* d_ws, size_t ws_size,
                              hipStream_t stream) {
    const float* x       = (const float*)d_in[0];
    const float* logits  = (const float*)d_in[1];
    const int*   w13q    = (const int*)d_in[2];
    const int*   w2q     = (const int*)d_in[3];
    const float* alpha13 = (const float*)d_in[4];
    const float* alpha2  = (const float*)d_in[5];
    float* out = (float*)d_out;

    char* ws = (char*)d_ws;
    u16* wb13 = (u16*)(ws);                         // 50331648 B
    u16* wb2  = (u16*)(ws + 50331648);              // 25165824 B
    u16* xb   = (u16*)(ws + 75497472);              // 16777216 B
    u16* ab   = (u16*)(ws + 92274688);              // 12582912 B
    u16* yb   = (u16*)(ws + 104857600);             // 33554432 B
    int* pairTok = (int*)(ws + 138412032);          // 8192 ints
    int* tid2    = pairTok + NPAIR;                 // 8192 ints
    float* tw    = (float*)(tid2 + NPAIR);          // 8192 floats
    int* counts  = (int*)(tw + NPAIR);              // 8
    int* offsets = counts + 8;                      // 9
    int* cursors = offsets + 9;                     // 8

    // routing
    k_zero<<<1, 64, 0, stream>>>(counts, 25);
    k_route<<<T_ / 256, 256, 0, stream>>>(logits, tid2, tw, counts);
    k_scan<<<1, 64, 0, stream>>>(counts, offsets);
    k_lists<<<T_ / 256, 256, 0, stream>>>(tid2, offsets, cursors, pairTok);

    // dequant
    k_cvt_w13<<<(8L * TWOI * K_) / 8 / 256, 256, 0, stream>>>(w13q, alpha13, wb13);
    k_cvt_w2<<<(8L * K_ * I_) / 8 / 256, 256, 0, stream>>>(w2q, alpha2, wb2);
    k_cvt_x<<<((long)T_ * K_) / 8 / 256, 256, 0, stream>>>(x, xb);

    // grouped GEMM1 + activation (1D grid, expert = bid & 7 -> XCD locality)
    k_gemm1<<<8 * (I_ / 64) * (T_ / BM), 256, 0, stream>>>(xb, wb13, pairTok, offsets, ab);

    // grouped GEMM2
    k_gemm2<<<8 * (K_ / 128) * (T_ / BM), 256, 0, stream>>>(ab, wb2, pairTok, offsets, yb);

    // combine
    k_combine<<<((long)T_ * K_) / 8 / 256, 256, 0, stream>>>(yb, tw, out);
}

// Round 5
// 341.349 us; speedup vs baseline: 1.3463x; 1.3463x over previous
//
#include <hip/hip_runtime.h>
#include <math.h>

#define E_ 8
#define T_ 4096
#define K_ 2048
#define I_ 768
#define TWOI 1536
#define NPAIR (2*T_)

typedef unsigned short u16;
typedef __attribute__((ext_vector_type(8))) __bf16 bf16x8;
typedef __attribute__((ext_vector_type(4))) float f32x4;
typedef __attribute__((ext_vector_type(8))) u16 u16x8;
typedef __attribute__((ext_vector_type(4))) int int4v;
typedef __attribute__((ext_vector_type(4))) float float4v;

typedef __attribute__((address_space(3))) u16 lds_u16;
typedef __attribute__((address_space(1))) const u16 g_u16;

__device__ inline void gld16(const u16* g, u16* l) {
    __builtin_amdgcn_global_load_lds((g_u16*)g, (lds_u16*)l, 16, 0, 0);
}

__device__ inline u16 f2bf(float x) {
    unsigned u = __builtin_bit_cast(unsigned, x);
    unsigned r = 0x7fffu + ((u >> 16) & 1u);
    u += r;
    return (u16)(u >> 16);
}
__device__ inline float bf2f(u16 b) {
    unsigned u = ((unsigned)b) << 16;
    return __builtin_bit_cast(float, u);
}

// ---------------- routing ----------------
__global__ void k_zero(int* __restrict__ p, int n) {
    int i = blockIdx.x * 256 + threadIdx.x;
    if (i < n) p[i] = 0;
}

__global__ void k_route(const float* __restrict__ logits, int* __restrict__ tid2,
                        float* __restrict__ tw, int* __restrict__ counts) {
    int t = blockIdx.x * 256 + threadIdx.x;
    if (t >= T_) return;
    float l[E_];
#pragma unroll
    for (int e = 0; e < E_; ++e) l[e] = logits[t * E_ + e];
    int i0 = 0; float m0 = l[0];
#pragma unroll
    for (int e = 1; e < E_; ++e) if (l[e] > m0) { m0 = l[e]; i0 = e; }
    int i1 = -1; float m1 = -1e30f;
#pragma unroll
    for (int e = 0; e < E_; ++e) if (e != i0 && l[e] > m1) { m1 = l[e]; i1 = e; }
    float w0 = 1.0f / (1.0f + expf(m1 - m0));
    float w1 = 1.0f - w0;
    tid2[t * 2 + 0] = i0; tid2[t * 2 + 1] = i1;
    tw[t * 2 + 0] = w0;  tw[t * 2 + 1] = w1;
    atomicAdd(&counts[i0], 1);
    atomicAdd(&counts[i1], 1);
}

__global__ void k_scan(const int* __restrict__ counts, int* __restrict__ offsets) {
    if (threadIdx.x == 0) {
        int s = 0;
        for (int e = 0; e < E_; ++e) { offsets[e] = s; s += counts[e]; }
        offsets[E_] = s;
    }
}

__global__ void k_lists(const int* __restrict__ tid2, const int* __restrict__ offsets,
                        int* __restrict__ cursors, int* __restrict__ pairTok) {
    int t = blockIdx.x * 256 + threadIdx.x;
    if (t >= T_) return;
#pragma unroll
    for (int s = 0; s < 2; ++s) {
        int e = tid2[t * 2 + s];
        int pos = atomicAdd(&cursors[e], 1);
        pairTok[offsets[e] + pos] = (t << 1) | s;
    }
}

// ---------------- dequant conversions ----------------
__global__ void k_cvt_w13(const int* __restrict__ q, const float* __restrict__ alpha,
                          u16* __restrict__ wb) {
    long idx = ((long)blockIdx.x * 256 + threadIdx.x) * 8;
    int k = (int)(idx & (K_ - 1));
    int e = (int)(idx / ((long)TWOI * K_));
    const int4v* qp = (const int4v*)(q + idx);
    int4v q0 = qp[0], q1 = qp[1];
    const float4v* ap = (const float4v*)(alpha + e * K_ + k);
    float4v a0 = ap[0], a1 = ap[1];
    u16x8 r;
    r[0] = f2bf((float)(q0[0] - 1) * a0[0]);
    r[1] = f2bf((float)(q0[1] - 1) * a0[1]);
    r[2] = f2bf((float)(q0[2] - 1) * a0[2]);
    r[3] = f2bf((float)(q0[3] - 1) * a0[3]);
    r[4] = f2bf((float)(q1[0] - 1) * a1[0]);
    r[5] = f2bf((float)(q1[1] - 1) * a1[1]);
    r[6] = f2bf((float)(q1[2] - 1) * a1[2]);
    r[7] = f2bf((float)(q1[3] - 1) * a1[3]);
    *(u16x8*)(wb + idx) = r;
}

__global__ void k_cvt_w2(const int* __restrict__ q, const float* __restrict__ alpha,
                         u16* __restrict__ wb) {
    long idx = ((long)blockIdx.x * 256 + threadIdx.x) * 8;
    int i = (int)(idx % I_);
    int e = (int)(idx / ((long)K_ * I_));
    const int4v* qp = (const int4v*)(q + idx);
    int4v q0 = qp[0], q1 = qp[1];
    const float4v* ap = (const float4v*)(alpha + e * I_ + i);
    float4v a0 = ap[0], a1 = ap[1];
    u16x8 r;
    r[0] = f2bf((float)(q0[0] - 1) * a0[0]);
    r[1] = f2bf((float)(q0[1] - 1) * a0[1]);
    r[2] = f2bf((float)(q0[2] - 1) * a0[2]);
    r[3] = f2bf((float)(q0[3] - 1) * a0[3]);
    r[4] = f2bf((float)(q1[0] - 1) * a1[0]);
    r[5] = f2bf((float)(q1[1] - 1) * a1[1]);
    r[6] = f2bf((float)(q1[2] - 1) * a1[2]);
    r[7] = f2bf((float)(q1[3] - 1) * a1[3]);
    *(u16x8*)(wb + idx) = r;
}

__global__ void k_cvt_x(const float* __restrict__ x, u16* __restrict__ xb) {
    long idx = ((long)blockIdx.x * 256 + threadIdx.x) * 8;
    const float4v* xp = (const float4v*)(x + idx);
    float4v x0 = xp[0], x1 = xp[1];
    u16x8 r;
    r[0] = f2bf(x0[0]); r[1] = f2bf(x0[1]); r[2] = f2bf(x0[2]); r[3] = f2bf(x0[3]);
    r[4] = f2bf(x1[0]); r[5] = f2bf(x1[1]); r[6] = f2bf(x1[2]); r[7] = f2bf(x1[3]);
    *(u16x8*)(xb + idx) = r;
}

#define BM 128
#define BK 64

// ---------------- grouped GEMM1 + silu*up ----------------
// 2-buffer (64KB, 2 blocks/CU) + T2 XOR swizzle (pre-swizzled source, swizzled read).
__global__ __launch_bounds__(256) void k_gemm1(
    const u16* __restrict__ xb,       // [T][K]
    const u16* __restrict__ wb13,     // [E][2I][K]
    const int* __restrict__ pairTok, const int* __restrict__ offsets,
    u16* __restrict__ ab)             // [NPAIR][I] (list order)
{
    int bid = blockIdx.x;
    int e = bid & 7;
    int r_ = bid >> 3;
    int n0 = (r_ >> 5) * 64;
    int m0 = (r_ & 31) * BM;

    int base = offsets[e];
    int cnt = offsets[e + 1] - base;
    if (m0 >= cnt) return;

    __shared__ __attribute__((aligned(16))) u16 As[2][BM][BK];  // 32 KB
    __shared__ __attribute__((aligned(16))) u16 Bg[2][64][BK];  // 16 KB
    __shared__ __attribute__((aligned(16))) u16 Bu[2][64][BK];  // 16 KB

    int tid = threadIdx.x;
    int lane = tid & 63, wid = tid >> 6;
    int wm = wid >> 1, wn = wid & 1;
    int lr = lane >> 3;                                   // row within 8-row chunk
    int lcs = (((lane & 7) ^ ((lane >> 3) & 7)) * 8);     // inverse-swizzled src col

    const u16* aSrc[4]; int aOff[4];
#pragma unroll
    for (int j = 0; j < 4; ++j) {
        int c = wid * 4 + j;                 // A chunk 0..15 (8 rows each)
        int m = m0 + c * 8 + lr;
        if (m >= cnt) m = cnt - 1;
        int tok = pairTok[base + m] >> 1;
        aSrc[j] = xb + (long)tok * K_ + lcs;
        aOff[j] = c * 512;
    }
    const u16* gSrc[2]; int bOff[2];
#pragma unroll
    for (int j = 0; j < 2; ++j) {
        int c = wid * 2 + j;                 // B chunk 0..7
        int row = n0 + c * 8 + lr;
        gSrc[j] = wb13 + ((long)e * TWOI + row) * K_ + lcs;
        bOff[j] = c * 512;
    }

    f32x4 accg[4][2], accu[4][2];
#pragma unroll
    for (int mi = 0; mi < 4; ++mi)
#pragma unroll
        for (int ni = 0; ni < 2; ++ni) {
            accg[mi][ni] = (f32x4){0.f, 0.f, 0.f, 0.f};
            accu[mi][ni] = (f32x4){0.f, 0.f, 0.f, 0.f};
        }

    auto stage = [&](int b, int k0) {
#pragma unroll
        for (int j = 0; j < 4; ++j) gld16(aSrc[j] + k0, &As[b][0][0] + aOff[j]);
#pragma unroll
        for (int j = 0; j < 2; ++j) {
            gld16(gSrc[j] + k0, &Bg[b][0][0] + bOff[j]);
            gld16(gSrc[j] + (long)I_ * K_ + k0, &Bu[b][0][0] + bOff[j]);
        }
    };

    int swz = (lane & 7) << 3;  // read-col XOR (elements)
    auto compute = [&](int b) {
#pragma unroll
        for (int kk = 0; kk < 2; ++kk) {
            int kc = (kk * 32 + (lane >> 4) * 8) ^ swz;
            bf16x8 aF[4], bgF[2], buF[2];
#pragma unroll
            for (int mi = 0; mi < 4; ++mi)
                aF[mi] = __builtin_bit_cast(bf16x8,
                    *(const u16x8*)&As[b][wm * 64 + mi * 16 + (lane & 15)][kc]);
#pragma unroll
            for (int ni = 0; ni < 2; ++ni) {
                bgF[ni] = __builtin_bit_cast(bf16x8,
                    *(const u16x8*)&Bg[b][wn * 32 + ni * 16 + (lane & 15)][kc]);
                buF[ni] = __builtin_bit_cast(bf16x8,
                    *(const u16x8*)&Bu[b][wn * 32 + ni * 16 + (lane & 15)][kc]);
            }
#pragma unroll
            for (int mi = 0; mi < 4; ++mi)
#pragma unroll
                for (int ni = 0; ni < 2; ++ni) {
                    accg[mi][ni] = __builtin_amdgcn_mfma_f32_16x16x32_bf16(
                        aF[mi], bgF[ni], accg[mi][ni], 0, 0, 0);
                    accu[mi][ni] = __builtin_amdgcn_mfma_f32_16x16x32_bf16(
                        aF[mi], buF[ni], accu[mi][ni], 0, 0, 0);
                }
        }
    };

    // 2-phase double-buffered pipeline, NT = K_/BK = 32 (even)
    stage(0, 0);
    __syncthreads();
#pragma unroll 1
    for (int t = 0; t < K_ / BK; t += 2) {
        stage(1, (t + 1) * BK);
        compute(0);
        __syncthreads();
        if (t + 2 < K_ / BK) stage(0, (t + 2) * BK);
        compute(1);
        __syncthreads();
    }

#pragma unroll
    for (int mi = 0; mi < 4; ++mi)
#pragma unroll
        for (int ni = 0; ni < 2; ++ni)
#pragma unroll
            for (int rg = 0; rg < 4; ++rg) {
                int r = wm * 64 + mi * 16 + (lane >> 4) * 4 + rg;
                if (m0 + r < cnt) {
                    int n = n0 + wn * 32 + ni * 16 + (lane & 15);
                    float g = accg[mi][ni][rg];
                    float u = accu[mi][ni][rg];
                    float a = g / (1.0f + expf(-g)) * u;
                    ab[(long)(base + m0 + r) * I_ + n] = f2bf(a);
                }
            }
}

// ---------------- grouped GEMM2 (128x128, 2-buffer + swizzle) ----------------
__global__ __launch_bounds__(256) void k_gemm2(
    const u16* __restrict__ ab,       // [NPAIR][I] (list order)
    const u16* __restrict__ wb2,      // [E][K][I]
    const int* __restrict__ pairTok, const int* __restrict__ offsets,
    u16* __restrict__ yb)             // [NPAIR][K] indexed by (t<<1)|slot
{
    int bid = blockIdx.x;
    int e = bid & 7;
    int r_ = bid >> 3;
    int n0 = (r_ >> 5) * 128;
    int m0 = (r_ & 31) * BM;

    int base = offsets[e];
    int cnt = offsets[e + 1] - base;
    if (m0 >= cnt) return;

    __shared__ __attribute__((aligned(16))) u16 As[2][BM][BK];   // 32 KB
    __shared__ __attribute__((aligned(16))) u16 Bs[2][128][BK];  // 32 KB

    int tid = threadIdx.x;
    int lane = tid & 63, wid = tid >> 6;
    int wm = wid >> 1, wn = wid & 1;
    int lr = lane >> 3;
    int lcs = (((lane & 7) ^ ((lane >> 3) & 7)) * 8);

    const u16* aSrc[4]; int aOff[4];
#pragma unroll
    for (int j = 0; j < 4; ++j) {
        int c = wid * 4 + j;
        int m = m0 + c * 8 + lr;
        if (m >= cnt) m = cnt - 1;
        aSrc[j] = ab + (long)(base + m) * I_ + lcs;
        aOff[j] = c * 512;
    }
    const u16* bSrc[4]; int bOff[4];
#pragma unroll
    for (int j = 0; j < 4; ++j) {
        int c = wid * 4 + j;
        int row = n0 + c * 8 + lr;
        bSrc[j] = wb2 + ((long)e * K_ + row) * I_ + lcs;
        bOff[j] = c * 512;
    }

    f32x4 acc[4][4];
#pragma unroll
    for (int mi = 0; mi < 4; ++mi)
#pragma unroll
        for (int ni = 0; ni < 4; ++ni)
            acc[mi][ni] = (f32x4){0.f, 0.f, 0.f, 0.f};

    auto stage = [&](int b, int k0) {
#pragma unroll
        for (int j = 0; j < 4; ++j) gld16(aSrc[j] + k0, &As[b][0][0] + aOff[j]);
#pragma unroll
        for (int j = 0; j < 4; ++j) gld16(bSrc[j] + k0, &Bs[b][0][0] + bOff[j]);
    };

    int swz = (lane & 7) << 3;
    auto compute = [&](int b) {
#pragma unroll
        for (int kk = 0; kk < 2; ++kk) {
            int kc = (kk * 32 + (lane >> 4) * 8) ^ swz;
            bf16x8 aF[4], bF[4];
#pragma unroll
            for (int mi = 0; mi < 4; ++mi)
                aF[mi] = __builtin_bit_cast(bf16x8,
                    *(const u16x8*)&As[b][wm * 64 + mi * 16 + (lane & 15)][kc]);
#pragma unroll
            for (int ni = 0; ni < 4; ++ni)
                bF[ni] = __builtin_bit_cast(bf16x8,
                    *(const u16x8*)&Bs[b][wn * 64 + ni * 16 + (lane & 15)][kc]);
#pragma unroll
            for (int mi = 0; mi < 4; ++mi)
#pragma unroll
                for (int ni = 0; ni < 4; ++ni)
                    acc[mi][ni] = __builtin_amdgcn_mfma_f32_16x16x32_bf16(
                        aF[mi], bF[ni], acc[mi][ni], 0, 0, 0);
        }
    };

    // NT = I_/BK = 12 (even)
    stage(0, 0);
    __syncthreads();
#pragma unroll 1
    for (int t = 0; t < I_ / BK; t += 2) {
        stage(1, (t + 1) * BK);
        compute(0);
        __syncthreads();
        if (t + 2 < I_ / BK) stage(0, (t + 2) * BK);
        compute(1);
        __syncthreads();
    }

#pragma unroll
    for (int mi = 0; mi < 4; ++mi)
#pragma unroll
        for (int ni = 0; ni < 4; ++ni)
#pragma unroll
            for (int rg = 0; rg < 4; ++rg) {
                int r = wm * 64 + mi * 16 + (lane >> 4) * 4 + rg;
                if (m0 + r < cnt) {
                    int pt = pairTok[base + m0 + r];
                    int n = n0 + wn * 64 + ni * 16 + (lane & 15);
                    yb[(long)pt * K_ + n] = f2bf(acc[mi][ni][rg]);
                }
            }
}

// ---------------- combine ----------------
__global__ void k_combine(const u16* __restrict__ yb, const float* __restrict__ tw,
                          float* __restrict__ out) {
    long idx = ((long)blockIdx.x * 256 + threadIdx.x) * 8;
    int t = (int)(idx >> 11);
    float w0 = tw[t * 2 + 0];
    float w1 = tw[t * 2 + 1];
    u16x8 y0 = *(const u16x8*)(yb + (long)(2 * t) * K_ + (idx & (K_ - 1)));
    u16x8 y1 = *(const u16x8*)(yb + (long)(2 * t + 1) * K_ + (idx & (K_ - 1)));
    float4v o0, o1;
#pragma unroll
    for (int j = 0; j < 4; ++j) o0[j] = w0 * bf2f(y0[j]) + w1 * bf2f(y1[j]);
#pragma unroll
    for (int j = 0; j < 4; ++j) o1[j] = w0 * bf2f(y0[4 + j]) + w1 * bf2f(y1[4 + j]);
    *(float4v*)(out + idx) = o0;
    *(float4v*)(out + idx + 4) = o1;
}

// ---------------- launch ----------------
extern "C" void kernel_launch(void* const* d_in, const int* in_sizes, int n_in,
                              void* d_out, int out_size, void* d_ws, size_t ws_size,
                              hipStream_t stream) {
    const float* x       = (const float*)d_in[0];
    const float* logits  = (const float*)d_in[1];
    const int*   w13q    = (const int*)d_in[2];
    const int*   w2q     = (const int*)d_in[3];
    const float* alpha13 = (const float*)d_in[4];
    const float* alpha2  = (const float*)d_in[5];
    float* out = (float*)d_out;

    char* ws = (char*)d_ws;
    u16* wb13 = (u16*)(ws);                         // 50331648 B
    u16* wb2  = (u16*)(ws + 50331648);              // 25165824 B
    u16* xb   = (u16*)(ws + 75497472);              // 16777216 B
    u16* ab   = (u16*)(ws + 92274688);              // 12582912 B
    u16* yb   = (u16*)(ws + 104857600);             // 33554432 B
    int* pairTok = (int*)(ws + 138412032);          // 8192 ints
    int* tid2    = pairTok + NPAIR;                 // 8192 ints
    float* tw    = (float*)(tid2 + NPAIR);          // 8192 floats
    int* counts  = (int*)(tw + NPAIR);              // 8
    int* offsets = counts + 8;                      // 9
    int* cursors = offsets + 9;                     // 8

    // routing
    k_zero<<<1, 64, 0, stream>>>(counts, 25);
    k_route<<<T_ / 256, 256, 0, stream>>>(logits, tid2, tw, counts);
    k_scan<<<1, 64, 0, stream>>>(counts, offsets);
    k_lists<<<T_ / 256, 256, 0, stream>>>(tid2, offsets, cursors, pairTok);

    // dequant
    k_cvt_w13<<<(8L * TWOI * K_) / 8 / 256, 256, 0, stream>>>(w13q, alpha13, wb13);
    k_cvt_w2<<<(8L * K_ * I_) / 8 / 256, 256, 0, stream>>>(w2q, alpha2, wb2);
    k_cvt_x<<<((long)T_ * K_) / 8 / 256, 256, 0, stream>>>(x, xb);

    // grouped GEMM1 + activation (1D grid, expert = bid & 7 -> XCD locality)
    k_gemm1<<<8 * (I_ / 64) * (T_ / BM), 256, 0, stream>>>(xb, wb13, pairTok, offsets, ab);

    // grouped GEMM2
    k_gemm2<<<8 * (K_ / 128) * (T_ / BM), 256, 0, stream>>>(ab, wb2, pairTok, offsets, yb);

    // combine
    k_combine<<<((long)T_ * K_) / 8 / 256, 256, 0, stream>>>(yb, tw, out);
}

// Round 6
// 295.684 us; speedup vs baseline: 1.5542x; 1.1544x over previous
//
#include <hip/hip_runtime.h>
#include <math.h>

#define E_ 8
#define T_ 4096
#define K_ 2048
#define I_ 768
#define TWOI 1536
#define NPAIR (2*T_)

typedef unsigned short u16;
typedef __attribute__((ext_vector_type(8))) __bf16 bf16x8;
typedef __attribute__((ext_vector_type(4))) float f32x4;
typedef __attribute__((ext_vector_type(8))) u16 u16x8;
typedef __attribute__((ext_vector_type(4))) int int4v;
typedef __attribute__((ext_vector_type(4))) float float4v;

typedef __attribute__((address_space(3))) u16 lds_u16;
typedef __attribute__((address_space(1))) const u16 g_u16;

__device__ inline void gld16(const u16* g, u16* l) {
    __builtin_amdgcn_global_load_lds((g_u16*)g, (lds_u16*)l, 16, 0, 0);
}

#define FENCE asm volatile("" ::: "memory")
#define BARR do { FENCE; __builtin_amdgcn_s_barrier(); __builtin_amdgcn_sched_barrier(0); } while (0)
#define VM6  asm volatile("s_waitcnt vmcnt(6)" ::: "memory")

__device__ inline u16 f2bf(float x) {
    unsigned u = __builtin_bit_cast(unsigned, x);
    unsigned r = 0x7fffu + ((u >> 16) & 1u);
    u += r;
    return (u16)(u >> 16);
}
__device__ inline float bf2f(u16 b) {
    unsigned u = ((unsigned)b) << 16;
    return __builtin_bit_cast(float, u);
}

// ---------------- routing ----------------
__global__ void k_zero(int* __restrict__ p, int n) {
    int i = blockIdx.x * 256 + threadIdx.x;
    if (i < n) p[i] = 0;
}

__global__ void k_route(const float* __restrict__ logits, int* __restrict__ tid2,
                        float* __restrict__ tw, int* __restrict__ counts) {
    int t = blockIdx.x * 256 + threadIdx.x;
    if (t >= T_) return;
    float l[E_];
#pragma unroll
    for (int e = 0; e < E_; ++e) l[e] = logits[t * E_ + e];
    int i0 = 0; float m0 = l[0];
#pragma unroll
    for (int e = 1; e < E_; ++e) if (l[e] > m0) { m0 = l[e]; i0 = e; }
    int i1 = -1; float m1 = -1e30f;
#pragma unroll
    for (int e = 0; e < E_; ++e) if (e != i0 && l[e] > m1) { m1 = l[e]; i1 = e; }
    float w0 = 1.0f / (1.0f + expf(m1 - m0));
    float w1 = 1.0f - w0;
    tid2[t * 2 + 0] = i0; tid2[t * 2 + 1] = i1;
    tw[t * 2 + 0] = w0;  tw[t * 2 + 1] = w1;
    atomicAdd(&counts[i0], 1);
    atomicAdd(&counts[i1], 1);
}

__global__ void k_scan(const int* __restrict__ counts, int* __restrict__ offsets) {
    if (threadIdx.x == 0) {
        int s = 0;
        for (int e = 0; e < E_; ++e) { offsets[e] = s; s += counts[e]; }
        offsets[E_] = s;
    }
}

__global__ void k_lists(const int* __restrict__ tid2, const int* __restrict__ offsets,
                        int* __restrict__ cursors, int* __restrict__ pairTok) {
    int t = blockIdx.x * 256 + threadIdx.x;
    if (t >= T_) return;
#pragma unroll
    for (int s = 0; s < 2; ++s) {
        int e = tid2[t * 2 + s];
        int pos = atomicAdd(&cursors[e], 1);
        pairTok[offsets[e] + pos] = (t << 1) | s;
    }
}

// ---------------- dequant conversions ----------------
__global__ void k_cvt_w13(const int* __restrict__ q, const float* __restrict__ alpha,
                          u16* __restrict__ wb) {
    long idx = ((long)blockIdx.x * 256 + threadIdx.x) * 8;
    int k = (int)(idx & (K_ - 1));
    int e = (int)(idx / ((long)TWOI * K_));
    const int4v* qp = (const int4v*)(q + idx);
    int4v q0 = qp[0], q1 = qp[1];
    const float4v* ap = (const float4v*)(alpha + e * K_ + k);
    float4v a0 = ap[0], a1 = ap[1];
    u16x8 r;
    r[0] = f2bf((float)(q0[0] - 1) * a0[0]);
    r[1] = f2bf((float)(q0[1] - 1) * a0[1]);
    r[2] = f2bf((float)(q0[2] - 1) * a0[2]);
    r[3] = f2bf((float)(q0[3] - 1) * a0[3]);
    r[4] = f2bf((float)(q1[0] - 1) * a1[0]);
    r[5] = f2bf((float)(q1[1] - 1) * a1[1]);
    r[6] = f2bf((float)(q1[2] - 1) * a1[2]);
    r[7] = f2bf((float)(q1[3] - 1) * a1[3]);
    *(u16x8*)(wb + idx) = r;
}

__global__ void k_cvt_w2(const int* __restrict__ q, const float* __restrict__ alpha,
                         u16* __restrict__ wb) {
    long idx = ((long)blockIdx.x * 256 + threadIdx.x) * 8;
    int i = (int)(idx % I_);
    int e = (int)(idx / ((long)K_ * I_));
    const int4v* qp = (const int4v*)(q + idx);
    int4v q0 = qp[0], q1 = qp[1];
    const float4v* ap = (const float4v*)(alpha + e * I_ + i);
    float4v a0 = ap[0], a1 = ap[1];
    u16x8 r;
    r[0] = f2bf((float)(q0[0] - 1) * a0[0]);
    r[1] = f2bf((float)(q0[1] - 1) * a0[1]);
    r[2] = f2bf((float)(q0[2] - 1) * a0[2]);
    r[3] = f2bf((float)(q0[3] - 1) * a0[3]);
    r[4] = f2bf((float)(q1[0] - 1) * a1[0]);
    r[5] = f2bf((float)(q1[1] - 1) * a1[1]);
    r[6] = f2bf((float)(q1[2] - 1) * a1[2]);
    r[7] = f2bf((float)(q1[3] - 1) * a1[3]);
    *(u16x8*)(wb + idx) = r;
}

__global__ void k_cvt_x(const float* __restrict__ x, u16* __restrict__ xb) {
    long idx = ((long)blockIdx.x * 256 + threadIdx.x) * 8;
    const float4v* xp = (const float4v*)(x + idx);
    float4v x0 = xp[0], x1 = xp[1];
    u16x8 r;
    r[0] = f2bf(x0[0]); r[1] = f2bf(x0[1]); r[2] = f2bf(x0[2]); r[3] = f2bf(x0[3]);
    r[4] = f2bf(x1[0]); r[5] = f2bf(x1[1]); r[6] = f2bf(x1[2]); r[7] = f2bf(x1[3]);
    *(u16x8*)(xb + idx) = r;
}

// ---------------- 256x256 8-phase grouped GEMM template ----------------
// C[m][n] = sum_k A[m][k] * B[n][k]   (B^T layout, both row-major stride KD)
// GATHER: A rows via pairTok>>1; else A row = base+m (list order)
// SCATTER: C rows via pairTok (token<<1|slot); else C row = base+m
template<int KD, int NCH, int NT, bool GATHER, bool SCATTER>
__global__ __launch_bounds__(512, 2) void k_gemm8(
    const u16* __restrict__ A, const u16* __restrict__ B,
    const int* __restrict__ pairTok, const int* __restrict__ offsets,
    u16* __restrict__ C)
{
    constexpr int ND = NCH * 256;
    int bid = blockIdx.x;
    int mc = bid / (8 * NCH);
    int e  = (bid / NCH) & 7;
    int n0 = (bid % NCH) * 256;
    int base = offsets[e];
    int cnt  = offsets[e + 1] - base;
    int m0 = mc * 256;
    if (m0 >= cnt) return;

    __shared__ __attribute__((aligned(16))) u16 As[2][256][64];  // 64 KB
    __shared__ __attribute__((aligned(16))) u16 Bs[2][256][64];  // 64 KB

    int tid = threadIdx.x;
    int lane = tid & 63;
    int wid = tid >> 6;          // 0..7
    int wr = wid >> 2, wc = wid & 3;
    int l15 = lane & 15;

    // --- staging source pointers (pre-swizzled global col; linear LDS dest) ---
    const u16* srcA[2][2];
    const u16* srcB[2][2];
#pragma unroll
    for (int h = 0; h < 2; ++h)
#pragma unroll
        for (int j = 0; j < 2; ++j) {
            int slot = j * 512 + tid;
            int row = slot >> 3, ch = slot & 7;
            int colsw = (ch ^ (row & 7)) * 8;
            int ra = m0 + h * 128 + row;
            if (ra >= cnt) ra = cnt - 1;
            long arow = GATHER ? (long)(pairTok[base + ra] >> 1) : (long)(base + ra);
            srcA[h][j] = A + arow * KD + colsw;
            srcB[h][j] = B + ((long)e * ND + n0 + h * 128 + row) * (long)KD + colsw;
        }
    u16* ldsA = &As[0][0][0];
    u16* ldsB = &Bs[0][0][0];
    int d0 = tid * 8, d1 = (512 + tid) * 8;

    auto stA = [&](int bs, int h, int t) {
        int k0 = (t < NT ? t : 0) * 64;
        u16* d = ldsA + bs * 16384 + h * 8192;
        gld16(srcA[h][0] + k0, d + d0);
        gld16(srcA[h][1] + k0, d + d1);
    };
    auto stB = [&](int bs, int h, int t) {
        int k0 = (t < NT ? t : 0) * 64;
        u16* d = ldsB + bs * 16384 + h * 8192;
        gld16(srcB[h][0] + k0, d + d0);
        gld16(srcB[h][1] + k0, d + d1);
    };

    int kc0 = ((((lane >> 4) & 3) * 8)) ^ ((lane & 7) * 8);
    int kc1 = (32 + (((lane >> 4) & 3) * 8)) ^ ((lane & 7) * 8);

    bf16x8 a[4][2], b[4][2];
    f32x4 acc[8][4];
#pragma unroll
    for (int mf = 0; mf < 8; ++mf)
#pragma unroll
        for (int nf = 0; nf < 4; ++nf)
            acc[mf][nf] = (f32x4){0.f, 0.f, 0.f, 0.f};

    auto rdA = [&](int bs, int h64) {
#pragma unroll
        for (int mf = 0; mf < 4; ++mf) {
            const u16* p = ldsA + bs * 16384 + (wr * 128 + h64 + mf * 16 + l15) * 64;
            a[mf][0] = __builtin_bit_cast(bf16x8, *(const u16x8*)(p + kc0));
            a[mf][1] = __builtin_bit_cast(bf16x8, *(const u16x8*)(p + kc1));
        }
    };
    auto rdB = [&](int bs) {
#pragma unroll
        for (int nf = 0; nf < 4; ++nf) {
            const u16* p = ldsB + bs * 16384 + (wc * 64 + nf * 16 + l15) * 64;
            b[nf][0] = __builtin_bit_cast(bf16x8, *(const u16x8*)(p + kc0));
            b[nf][1] = __builtin_bit_cast(bf16x8, *(const u16x8*)(p + kc1));
        }
    };
    auto mmq = [&](int mh, int nh) {
        __builtin_amdgcn_s_setprio(1);
#pragma unroll
        for (int mf = 0; mf < 4; ++mf)
#pragma unroll
            for (int nf = 0; nf < 2; ++nf)
#pragma unroll
                for (int ks = 0; ks < 2; ++ks)
                    acc[mh * 4 + mf][nh * 2 + nf] = __builtin_amdgcn_mfma_f32_16x16x32_bf16(
                        a[mf][ks], b[nh * 2 + nf][ks], acc[mh * 4 + mf][nh * 2 + nf], 0, 0, 0);
        __builtin_amdgcn_s_setprio(0);
    };

    // prologue: tile0 full + tile1 {B0,B1,A0}; vmcnt(6) forces tile0 landed
    stB(0, 0, 0); stB(0, 1, 0); stA(0, 0, 0); stA(0, 1, 0);
    stB(1, 0, 1); stB(1, 1, 1); stA(1, 0, 1);
    VM6; BARR;

#pragma unroll 1
    for (int i = 0; i < NT / 2; ++i) {
        int tO = 2 * i + 1, t2 = 2 * i + 2, t3 = 2 * i + 3;
        // ph1: read E (buf0) A-lo + B-all; stage A1(O)->buf1
        rdA(0, 0); rdB(0);
        stA(1, 1, tO);
        BARR; mmq(0, 0); BARR;
        // ph2: stage B0(E')->buf0 (buf0 B dead after ph1)
        stB(0, 0, t2);
        BARR; mmq(0, 1); BARR;
        // ph3: read E A-hi (buf0 A rows +64); stage B1(E')
        rdA(0, 64);
        stB(0, 1, t2);
        BARR; mmq(1, 0); BARR;
        // ph4: stage A0(E'); vmcnt(6) -> tile O fully landed
        stA(0, 0, t2);
        VM6; BARR; mmq(1, 1); BARR;
        // ph5: read O (buf1) A-lo + B-all; stage A1(E')
        rdA(1, 0); rdB(1);
        stA(0, 1, t2);
        BARR; mmq(0, 0); BARR;
        // ph6: stage B0(O')->buf1 (buf1 B dead after ph5)
        stB(1, 0, t3);
        BARR; mmq(0, 1); BARR;
        // ph7: read O A-hi; stage B1(O')
        rdA(1, 64);
        stB(1, 1, t3);
        BARR; mmq(1, 0); BARR;
        // ph8: stage A0(O'); vmcnt(6) -> tile E' fully landed
        stA(1, 0, t3);
        VM6; BARR; mmq(1, 1); BARR;
    }

    // epilogue
#pragma unroll
    for (int mf = 0; mf < 8; ++mf)
#pragma unroll
        for (int nf = 0; nf < 4; ++nf)
#pragma unroll
            for (int rg = 0; rg < 4; ++rg) {
                int r = wr * 128 + mf * 16 + (lane >> 4) * 4 + rg;
                if (m0 + r < cnt) {
                    int col = n0 + wc * 64 + nf * 16 + l15;
                    u16 v = f2bf(acc[mf][nf][rg]);
                    if (SCATTER) {
                        int pt = pairTok[base + m0 + r];
                        C[(long)pt * ND + col] = v;
                    } else {
                        C[(long)(base + m0 + r) * ND + col] = v;
                    }
                }
            }
}

// ---------------- silu(g)*u activation ----------------
__global__ void k_act(const u16* __restrict__ h, u16* __restrict__ ab) {
    long idx = ((long)blockIdx.x * 256 + threadIdx.x) * 8;  // over NPAIR*I
    int p = (int)(idx / I_);
    int i = (int)(idx - (long)p * I_);
    u16x8 gv = *(const u16x8*)(h + (long)p * TWOI + i);
    u16x8 uv = *(const u16x8*)(h + (long)p * TWOI + I_ + i);
    u16x8 r;
#pragma unroll
    for (int j = 0; j < 8; ++j) {
        float g = bf2f(gv[j]);
        float u = bf2f(uv[j]);
        r[j] = f2bf(g / (1.0f + expf(-g)) * u);
    }
    *(u16x8*)(ab + (long)p * I_ + i) = r;
}

// ---------------- combine ----------------
__global__ void k_combine(const u16* __restrict__ yb, const float* __restrict__ tw,
                          float* __restrict__ out) {
    long idx = ((long)blockIdx.x * 256 + threadIdx.x) * 8;
    int t = (int)(idx >> 11);
    float w0 = tw[t * 2 + 0];
    float w1 = tw[t * 2 + 1];
    u16x8 y0 = *(const u16x8*)(yb + (long)(2 * t) * K_ + (idx & (K_ - 1)));
    u16x8 y1 = *(const u16x8*)(yb + (long)(2 * t + 1) * K_ + (idx & (K_ - 1)));
    float4v o0, o1;
#pragma unroll
    for (int j = 0; j < 4; ++j) o0[j] = w0 * bf2f(y0[j]) + w1 * bf2f(y1[j]);
#pragma unroll
    for (int j = 0; j < 4; ++j) o1[j] = w0 * bf2f(y0[4 + j]) + w1 * bf2f(y1[4 + j]);
    *(float4v*)(out + idx) = o0;
    *(float4v*)(out + idx + 4) = o1;
}

// ---------------- launch ----------------
extern "C" void kernel_launch(void* const* d_in, const int* in_sizes, int n_in,
                              void* d_out, int out_size, void* d_ws, size_t ws_size,
                              hipStream_t stream) {
    const float* x       = (const float*)d_in[0];
    const float* logits  = (const float*)d_in[1];
    const int*   w13q    = (const int*)d_in[2];
    const int*   w2q     = (const int*)d_in[3];
    const float* alpha13 = (const float*)d_in[4];
    const float* alpha2  = (const float*)d_in[5];
    float* out = (float*)d_out;

    char* ws = (char*)d_ws;
    u16* wb13 = (u16*)(ws);                         // 50331648 B
    u16* wb2  = (u16*)(ws + 50331648);              // 25165824 B
    u16* xb   = (u16*)(ws + 75497472);              // 16777216 B
    u16* ab   = (u16*)(ws + 92274688);              // 12582912 B
    u16* yb   = (u16*)(ws + 104857600);             // 33554432 B
    u16* h    = yb;                                 // aliases yb: h dead before gemm2 writes yb
    int* pairTok = (int*)(ws + 138412032);          // 8192 ints
    int* tid2    = pairTok + NPAIR;                 // 8192 ints
    float* tw    = (float*)(tid2 + NPAIR);          // 8192 floats
    int* counts  = (int*)(tw + NPAIR);              // 8
    int* offsets = counts + 8;                      // 9
    int* cursors = offsets + 9;                     // 8

    // routing
    k_zero<<<1, 64, 0, stream>>>(counts, 25);
    k_route<<<T_ / 256, 256, 0, stream>>>(logits, tid2, tw, counts);
    k_scan<<<1, 64, 0, stream>>>(counts, offsets);
    k_lists<<<T_ / 256, 256, 0, stream>>>(tid2, offsets, cursors, pairTok);

    // dequant
    k_cvt_w13<<<(8L * TWOI * K_) / 8 / 256, 256, 0, stream>>>(w13q, alpha13, wb13);
    k_cvt_w2<<<(8L * K_ * I_) / 8 / 256, 256, 0, stream>>>(w2q, alpha2, wb2);
    k_cvt_x<<<((long)T_ * K_) / 8 / 256, 256, 0, stream>>>(x, xb);

    // grouped GEMM1 (M x 1536 x 2048), 8-phase 256^2, gather A rows by token
    k_gemm8<K_, TWOI / 256, K_ / 64, true, false>
        <<<(T_ / 256) * 8 * (TWOI / 256), 512, 0, stream>>>(xb, wb13, pairTok, offsets, h);

    // silu(g)*u
    k_act<<<((long)NPAIR * I_) / 8 / 256, 256, 0, stream>>>(h, ab);

    // grouped GEMM2 (M x 2048 x 768), 8-phase 256^2, scatter C rows by pair
    k_gemm8<I_, K_ / 256, I_ / 64, false, true>
        <<<(T_ / 256) * 8 * (K_ / 256), 512, 0, stream>>>(ab, wb2, pairTok, offsets, yb);

    // combine
    k_combine<<<((long)T_ * K_) / 8 / 256, 256, 0, stream>>>(yb, tw, out);
}